// Round 1
// 1447.144 us; speedup vs baseline: 1.1370x; 1.1370x over previous
//
#include <hip/hip_runtime.h>
#include <hip/hip_bf16.h>

// Problem: B=2, S=2048, D=1024, H=16, DH=64.
// Inputs (fp32 per reference): x [2,2048,1024], mask int32 [2,2048,2048],
//   w*_w [1024,1024], w*_b [1024].
// d_out (fp32): out (2*2048*1024) ++ attn (2*16*2048*2048), flat.
// d_ws: q (8MB) | k (8MB) | Vt (8MB) bf16; ctx reuses q slot (safe: each wave
//   of the fused kernel reads exactly its own 16x64 Q block into registers at
//   start and writes exactly that block as ctx at the end). Needs 24 MB.

typedef __bf16 bf16_t;
typedef __bf16 bf16x8 __attribute__((ext_vector_type(8)));
typedef float f32x4 __attribute__((ext_vector_type(4)));
typedef float f32x8 __attribute__((ext_vector_type(8)));

#define MFMA16(a, b, c) __builtin_amdgcn_mfma_f32_16x16x32_bf16((a), (b), (c), 0, 0, 0)

// Verified gfx950 16x16x32 bf16 layouts (learn_hip m89/m91):
//   A-frag a[j] = A[m][k], m = lane&15, k = (lane>>4)*8 + j
//   B-frag b[j] = B[k][n], n = lane&15, k = (lane>>4)*8 + j
//   D-frag d[r] = D[row][col], col = lane&15, row = (lane>>4)*4 + r

__device__ inline bf16x8 loadfrag(const float* p) {
  f32x8 f = *(const f32x8*)p;
  bf16x8 o;
#pragma unroll
  for (int j = 0; j < 8; ++j) o[j] = (bf16_t)f[j];
  return o;
}
__device__ inline bf16x8 loadfrag(const bf16_t* p) { return *(const bf16x8*)p; }

// ---------------------------------------------------------------------------
// Projection GEMM: C[4096,1024] = A[4096,1024] * W[1024,1024]^T + bias
// A: fp32 (x) or bf16 (ctx). C: bf16 (ws) or fp32 (final out).
// MODE 0: row-major store. MODE 1: store V transposed per head:
//         Vt[((b*16+h)*64 + d)*2048 + s]
// Per wave: one 16x64 output stripe (4 n-tiles), K-step 32.
// ---------------------------------------------------------------------------
template <int MODE, typename TA, typename TC>
__global__ void gemm_bias_k(const TA* __restrict__ A,
                            const float* __restrict__ W,
                            const float* __restrict__ bias,
                            TC* __restrict__ C) {
  const int N = 1024, K = 1024;
  int wave = (blockIdx.x * blockDim.x + threadIdx.x) >> 6;  // 0..4095
  int lane = threadIdx.x & 63;
  int quad = lane >> 4, r = lane & 15;
  int tm = wave >> 4;   // 0..255
  int tn = wave & 15;   // 0..15
  int m0 = tm * 16, n0 = tn * 64;

  const TA* arow = A + (size_t)(m0 + r) * K + quad * 8;
  const float* wbase = W + (size_t)(n0 + r) * K + quad * 8;

  f32x4 acc[4] = {};
  for (int k0 = 0; k0 < K; k0 += 32) {
    bf16x8 af = loadfrag(arow + k0);
#pragma unroll
    for (int t = 0; t < 4; ++t) {
      bf16x8 bfr = loadfrag(wbase + (size_t)t * 16 * K + k0);
      acc[t] = MFMA16(af, bfr, acc[t]);
    }
  }
#pragma unroll
  for (int t = 0; t < 4; ++t) {
#pragma unroll
    for (int i = 0; i < 4; ++i) {
      int row = m0 + quad * 4 + i;
      int col = n0 + t * 16 + r;
      float v = acc[t][i] + bias[col];
      if (MODE == 0) {
        C[(size_t)row * N + col] = (TC)v;
      } else {
        int b = row >> 11, s = row & 2047;
        int h = col >> 6, d = col & 63;
        C[((size_t)(b * 16 + h) * 64 + d) * 2048 + s] = (TC)v;
      }
    }
  }
}

// ---------------------------------------------------------------------------
// Fused attention: scores -> online softmax -> attn write (once, NT) -> P*V.
// One wave per (b, h, 16-row q-stripe): 4096 waves = 1024 blocks x 256.
//
// Pass A: stream K-tiles, QK^T via MFMA, online (max, sumexp) per row kept as
//   per-lane partials over that lane's col subset; merged across the 16-lane
//   col group with 4 shfl_xor at the end (lanes in a quad then all hold the
//   stats for rows quad*4+i).
// Pass B: re-stream the same QK^T (K frags are L2-resident: 256 KB per head),
//   p = exp(s - M) * inv, write attn exactly once (nontemporal: never re-read),
//   transpose the 16x64 p-chunk through a per-wave LDS buffer (D-frag col is
//   in lane&15 but the PV A-frag needs the q-row there), MFMA-accumulate P*V.
// ctx written at the very end over this wave's own Q block (alias; hence Q and
// ctx are NOT __restrict__).
// ---------------------------------------------------------------------------
__global__ __launch_bounds__(256) void attn_fused_k(
    const bf16_t* Q, const bf16_t* __restrict__ Km,
    const bf16_t* __restrict__ Vt, const int* __restrict__ mask,
    float* __restrict__ attn, bf16_t* ctx) {
  __shared__ float T[4][16][68];  // per-wave transpose buffer, +4 pad: 2-way banks max

  int wid = threadIdx.x >> 6;
  int lane = threadIdx.x & 63;
  int quad = lane >> 4, r = lane & 15;
  int wave = blockIdx.x * 4 + wid;  // 0..4095
  int bh = wave >> 7;               // 0..31
  int tm = wave & 127;              // 0..127
  int b = bh >> 4, h = bh & 15;
  int m0 = tm * 16;

  // Q fragment for this wave's 16 rows (read once, lives in registers).
  const bf16_t* qrow = Q + (size_t)(b * 2048 + m0 + r) * 1024 + h * 64 + quad * 8;
  bf16x8 qf0 = *(const bf16x8*)(qrow);
  bf16x8 qf1 = *(const bf16x8*)(qrow + 32);

  const bf16_t* kbase = Km + (size_t)(b * 2048) * 1024 + h * 64 + quad * 8;
  const int* mrow = mask + (size_t)b * 2048 * 2048;
  float* arow = attn + (size_t)bh * 2048 * 2048;

  float m[4], s[4];
#pragma unroll
  for (int i = 0; i < 4; ++i) { m[i] = -3e38f; s[i] = 0.f; }

  // ---------------- Pass A: online row max / sumexp ----------------
  for (int n0 = 0; n0 < 2048; n0 += 64) {
    f32x4 acc[4] = {};
#pragma unroll
    for (int tt = 0; tt < 4; ++tt) {
      const bf16_t* kr = kbase + (size_t)(n0 + tt * 16 + r) * 1024;
      acc[tt] = MFMA16(qf0, *(const bf16x8*)kr, acc[tt]);
      acc[tt] = MFMA16(qf1, *(const bf16x8*)(kr + 32), acc[tt]);
    }
    float sv[4][4];
#pragma unroll
    for (int tt = 0; tt < 4; ++tt)
#pragma unroll
      for (int i = 0; i < 4; ++i) {
        int row = m0 + quad * 4 + i;
        int col = n0 + tt * 16 + r;
        float v = acc[tt][i] * 0.125f;  // DH^-0.5
        if (mrow[(size_t)row * 2048 + col] == 0) v = -1e9f;
        sv[tt][i] = v;
      }
#pragma unroll
    for (int i = 0; i < 4; ++i) {
      float cm = fmaxf(fmaxf(sv[0][i], sv[1][i]), fmaxf(sv[2][i], sv[3][i]));
      float nm = fmaxf(m[i], cm);
      float a = __expf(sv[0][i] - nm) + __expf(sv[1][i] - nm) +
                __expf(sv[2][i] - nm) + __expf(sv[3][i] - nm);
      s[i] = s[i] * __expf(m[i] - nm) + a;
      m[i] = nm;
    }
  }

  // Merge (m, s) across the 16-lane column group.
#pragma unroll
  for (int i = 0; i < 4; ++i) {
#pragma unroll
    for (int off = 1; off < 16; off <<= 1) {
      float om = __shfl_xor(m[i], off);
      float os = __shfl_xor(s[i], off);
      float nm = fmaxf(m[i], om);
      s[i] = s[i] * __expf(m[i] - nm) + os * __expf(om - nm);
      m[i] = nm;
    }
  }
  float inv[4];
#pragma unroll
  for (int i = 0; i < 4; ++i) inv[i] = 1.f / s[i];

  // ---------------- Pass B: normalize, write attn, P*V ----------------
  const bf16_t* vbase = Vt + ((size_t)bh * 64 + r) * 2048 + quad * 8;
  f32x4 pv[4] = {};

  for (int n0 = 0; n0 < 2048; n0 += 64) {
    f32x4 acc[4] = {};
#pragma unroll
    for (int tt = 0; tt < 4; ++tt) {
      const bf16_t* kr = kbase + (size_t)(n0 + tt * 16 + r) * 1024;
      acc[tt] = MFMA16(qf0, *(const bf16x8*)kr, acc[tt]);
      acc[tt] = MFMA16(qf1, *(const bf16x8*)(kr + 32), acc[tt]);
    }
#pragma unroll
    for (int tt = 0; tt < 4; ++tt)
#pragma unroll
      for (int i = 0; i < 4; ++i) {
        int row = m0 + quad * 4 + i;
        int col = n0 + tt * 16 + r;
        float v = acc[tt][i] * 0.125f;
        if (mrow[(size_t)row * 2048 + col] == 0) v = -1e9f;
        float p = __expf(v - m[i]) * inv[i];
        __builtin_nontemporal_store(p, &arow[(size_t)row * 2048 + col]);
        T[wid][quad * 4 + i][tt * 16 + r] = p;
      }
    // PV: A-frag rows come from the transposed chunk (same-wave LDS, no barrier).
#pragma unroll
    for (int ks = 0; ks < 2; ++ks) {
      bf16x8 af = loadfrag(&T[wid][r][ks * 32 + quad * 8]);
#pragma unroll
      for (int tt2 = 0; tt2 < 4; ++tt2) {
        const bf16_t* vr = vbase + (size_t)tt2 * 16 * 2048 + n0 + ks * 32;
        pv[tt2] = MFMA16(af, *(const bf16x8*)vr, pv[tt2]);
      }
    }
  }

  // ctx epilogue: overwrite this wave's own Q block (bf16, row-major).
#pragma unroll
  for (int tt2 = 0; tt2 < 4; ++tt2)
#pragma unroll
    for (int i = 0; i < 4; ++i) {
      int row = m0 + quad * 4 + i;
      int col = tt2 * 16 + r;
      ctx[((size_t)b * 2048 + row) * 1024 + h * 64 + col] = (bf16_t)pv[tt2][i];
    }
}

extern "C" void kernel_launch(void* const* d_in, const int* in_sizes, int n_in,
                              void* d_out, int out_size, void* d_ws, size_t ws_size,
                              hipStream_t stream) {
  const float* x    = (const float*)d_in[0];
  const int*   mask = (const int*)d_in[1];
  const float* wq_w = (const float*)d_in[2];
  const float* wq_b = (const float*)d_in[3];
  const float* wk_w = (const float*)d_in[4];
  const float* wk_b = (const float*)d_in[5];
  const float* wv_w = (const float*)d_in[6];
  const float* wv_b = (const float*)d_in[7];
  const float* wo_w = (const float*)d_in[8];
  const float* wo_b = (const float*)d_in[9];

  float* out  = (float*)d_out;
  float* attn = out + (size_t)2 * 2048 * 1024;

  const size_t MB8 = (size_t)4096 * 1024;  // elements per 4096x1024 bf16 buffer
  bf16_t* qbuf = (bf16_t*)d_ws;
  bf16_t* kbuf = qbuf + MB8;
  bf16_t* vtb  = qbuf + 2 * MB8;
  bf16_t* ctx  = qbuf;  // reuse q slot (per-wave exact self-overwrite in fused kernel)

  dim3 blk(256);
  gemm_bias_k<0, float, bf16_t><<<1024, blk, 0, stream>>>(x, wq_w, wq_b, qbuf);
  gemm_bias_k<0, float, bf16_t><<<1024, blk, 0, stream>>>(x, wk_w, wk_b, kbuf);
  gemm_bias_k<1, float, bf16_t><<<1024, blk, 0, stream>>>(x, wv_w, wv_b, vtb);
  attn_fused_k<<<1024, blk, 0, stream>>>(qbuf, kbuf, vtb, mask, attn, ctx);
  gemm_bias_k<0, bf16_t, float><<<1024, blk, 0, stream>>>(ctx, wo_w, wo_b, out);
}

// Round 2
// 989.666 us; speedup vs baseline: 1.6626x; 1.4623x over previous
//
#include <hip/hip_runtime.h>
#include <hip/hip_bf16.h>

// Problem: B=2, S=2048, D=1024, H=16, DH=64.
// Inputs (fp32 per reference): x [2,2048,1024], mask int32 [2,2048,2048],
//   w*_w [1024,1024], w*_b [1024].
// d_out (fp32): out (2*2048*1024) ++ attn (2*16*2048*2048), flat.
// d_ws (24 MB): qbuf (8MB) | kbuf (8MB) | vtb (8MB) bf16.
//   ctx reuses qbuf (per-wave exact self-overwrite in fused kernel);
//   wo bf16 copy reuses kbuf AFTER attn_fused_k (kbuf dead by then).
// Pre-attn scratch (xb + wq/wk/wv bf16, 14 MB) lives in the attn OUTPUT
//   region, which is dead until attn_fused_k fully overwrites it.

typedef __bf16 bf16_t;
typedef __bf16 bf16x8 __attribute__((ext_vector_type(8)));
typedef float f32x4 __attribute__((ext_vector_type(4)));
typedef float f32x8 __attribute__((ext_vector_type(8)));

#define MFMA16(a, b, c) __builtin_amdgcn_mfma_f32_16x16x32_bf16((a), (b), (c), 0, 0, 0)

// Verified gfx950 16x16x32 bf16 layouts (learn_hip m89/m91):
//   A-frag a[j] = A[m][k], m = lane&15, k = (lane>>4)*8 + j
//   B-frag b[j] = B[k][n], n = lane&15, k = (lane>>4)*8 + j
//   D-frag d[r] = D[row][col], col = lane&15, row = (lane>>4)*4 + r

__device__ inline bf16x8 loadfrag(const float* p) {
  f32x8 f = *(const f32x8*)p;
  bf16x8 o;
#pragma unroll
  for (int j = 0; j < 8; ++j) o[j] = (bf16_t)f[j];
  return o;
}
__device__ inline bf16x8 loadfrag(const bf16_t* p) { return *(const bf16x8*)p; }

__device__ inline void gload16(const void* g, void* l) {
  __builtin_amdgcn_global_load_lds(
      (const __attribute__((address_space(1))) void*)g,
      (__attribute__((address_space(3))) void*)l, 16, 0, 0);
}

// ---------------------------------------------------------------------------
// fp32 -> bf16 conversion, 8 elems/thread, grid-stride.
// ---------------------------------------------------------------------------
__global__ void cvt_k(const float* __restrict__ src, bf16_t* __restrict__ dst,
                      int n8) {
  int i = blockIdx.x * blockDim.x + threadIdx.x;
  int stride = gridDim.x * blockDim.x;
  for (; i < n8; i += stride) {
    f32x8 f = *(const f32x8*)(src + (size_t)i * 8);
    bf16x8 o;
#pragma unroll
    for (int j = 0; j < 8; ++j) o[j] = (bf16_t)f[j];
    *(bf16x8*)(dst + (size_t)i * 8) = o;
  }
}

// ---------------------------------------------------------------------------
// Tiled projection GEMM: C[4096,1024] = A[4096,1024](bf16) * W^T(bf16) + bias.
// BM=128, BN=64, BK=32. 256 thr = 4 waves in 2x2; wave tile 64x32 (4x2 frags).
// LDS staged via global_load_lds width 16 (linear chunk map, guide §5 step 3).
// MODE 0: row-major store (TC bf16 or float).
// MODE 1: store V transposed per head: Vt[((b*16+h)*64+d)*2048 + s].
// ---------------------------------------------------------------------------
template <int MODE, typename TC>
__global__ __launch_bounds__(256) void gemm128_k(
    const bf16_t* __restrict__ A, const bf16_t* __restrict__ W,
    const float* __restrict__ bias, TC* __restrict__ C) {
  const int K = 1024, N = 1024;
  __shared__ bf16_t As[128 * 32];  // 8 KB
  __shared__ bf16_t Bs[64 * 32];   // 4 KB
  int tid = threadIdx.x;
  int wid = tid >> 6, lane = tid & 63;
  int quad = lane >> 4, r = lane & 15;
  int bm = blockIdx.x >> 4, bn = blockIdx.x & 15;
  int m0 = bm * 128, n0 = bn * 64;

  // Staging map: chunk c (16B) -> LDS byte 16c; row = c/4, col = (c%4)*8.
  // Wave-uniform LDS base + lane*16 is the HW-imposed layout (guide §5).
  const bf16_t* ga0 = A + (size_t)(m0 + (tid >> 2)) * K + (tid & 3) * 8;
  const bf16_t* ga1 = A + (size_t)(m0 + 64 + (tid >> 2)) * K + (tid & 3) * 8;
  const bf16_t* gb = W + (size_t)(n0 + (tid >> 2)) * K + (tid & 3) * 8;
  bf16_t* la0 = As + wid * 512;           // rows [wid*16, +16)
  bf16_t* la1 = As + 2048 + wid * 512;    // rows [64+wid*16, +16)
  bf16_t* lb = Bs + wid * 512;

  int wr = wid >> 1, wc = wid & 1;
  f32x4 acc[4][2] = {};

  for (int k0 = 0; k0 < K; k0 += 32) {
    __syncthreads();  // protect LDS from previous iteration's readers
    gload16(ga0 + k0, la0);
    gload16(ga1 + k0, la1);
    gload16(gb + k0, lb);
    __syncthreads();  // implies s_waitcnt vmcnt(0): staging complete

    bf16x8 a[4], b[2];
#pragma unroll
    for (int mi = 0; mi < 4; ++mi)
      a[mi] = *(const bf16x8*)(As + (wr * 64 + mi * 16 + r) * 32 + quad * 8);
#pragma unroll
    for (int ni = 0; ni < 2; ++ni)
      b[ni] = *(const bf16x8*)(Bs + (wc * 32 + ni * 16 + r) * 32 + quad * 8);
#pragma unroll
    for (int mi = 0; mi < 4; ++mi)
#pragma unroll
      for (int ni = 0; ni < 2; ++ni)
        acc[mi][ni] = MFMA16(a[mi], b[ni], acc[mi][ni]);
  }

#pragma unroll
  for (int mi = 0; mi < 4; ++mi)
#pragma unroll
    for (int ni = 0; ni < 2; ++ni)
#pragma unroll
      for (int i = 0; i < 4; ++i) {
        int row = m0 + wr * 64 + mi * 16 + quad * 4 + i;
        int col = n0 + wc * 32 + ni * 16 + r;
        float v = acc[mi][ni][i] + bias[col];
        if (MODE == 0) {
          C[(size_t)row * N + col] = (TC)v;
        } else {
          int b_ = row >> 11, s = row & 2047;
          int h = col >> 6, d = col & 63;
          C[((size_t)(b_ * 16 + h) * 64 + d) * 2048 + s] = (TC)v;
        }
      }
}

// ---------------------------------------------------------------------------
// Fused attention: scores -> online softmax -> attn write (once, NT) -> P*V.
// One wave per (b, h, 16-row q-stripe): 4096 waves = 1024 blocks x 256.
// (unchanged from round 1; see comments there)
// ---------------------------------------------------------------------------
__global__ __launch_bounds__(256) void attn_fused_k(
    const bf16_t* Q, const bf16_t* __restrict__ Km,
    const bf16_t* __restrict__ Vt, const int* __restrict__ mask,
    float* __restrict__ attn, bf16_t* ctx) {
  __shared__ float T[4][16][68];  // per-wave transpose buffer, +4 pad

  int wid = threadIdx.x >> 6;
  int lane = threadIdx.x & 63;
  int quad = lane >> 4, r = lane & 15;
  int wave = blockIdx.x * 4 + wid;  // 0..4095
  int bh = wave >> 7;               // 0..31
  int tm = wave & 127;              // 0..127
  int b = bh >> 4, h = bh & 15;
  int m0 = tm * 16;

  const bf16_t* qrow = Q + (size_t)(b * 2048 + m0 + r) * 1024 + h * 64 + quad * 8;
  bf16x8 qf0 = *(const bf16x8*)(qrow);
  bf16x8 qf1 = *(const bf16x8*)(qrow + 32);

  const bf16_t* kbase = Km + (size_t)(b * 2048) * 1024 + h * 64 + quad * 8;
  const int* mrow = mask + (size_t)b * 2048 * 2048;
  float* arow = attn + (size_t)bh * 2048 * 2048;

  float m[4], s[4];
#pragma unroll
  for (int i = 0; i < 4; ++i) { m[i] = -3e38f; s[i] = 0.f; }

  // ---------------- Pass A: online row max / sumexp ----------------
  for (int n0 = 0; n0 < 2048; n0 += 64) {
    f32x4 acc[4] = {};
#pragma unroll
    for (int tt = 0; tt < 4; ++tt) {
      const bf16_t* kr = kbase + (size_t)(n0 + tt * 16 + r) * 1024;
      acc[tt] = MFMA16(qf0, *(const bf16x8*)kr, acc[tt]);
      acc[tt] = MFMA16(qf1, *(const bf16x8*)(kr + 32), acc[tt]);
    }
    float sv[4][4];
#pragma unroll
    for (int tt = 0; tt < 4; ++tt)
#pragma unroll
      for (int i = 0; i < 4; ++i) {
        int row = m0 + quad * 4 + i;
        int col = n0 + tt * 16 + r;
        float v = acc[tt][i] * 0.125f;  // DH^-0.5
        if (mrow[(size_t)row * 2048 + col] == 0) v = -1e9f;
        sv[tt][i] = v;
      }
#pragma unroll
    for (int i = 0; i < 4; ++i) {
      float cm = fmaxf(fmaxf(sv[0][i], sv[1][i]), fmaxf(sv[2][i], sv[3][i]));
      float nm = fmaxf(m[i], cm);
      float a = __expf(sv[0][i] - nm) + __expf(sv[1][i] - nm) +
                __expf(sv[2][i] - nm) + __expf(sv[3][i] - nm);
      s[i] = s[i] * __expf(m[i] - nm) + a;
      m[i] = nm;
    }
  }

  // Merge (m, s) across the 16-lane column group.
#pragma unroll
  for (int i = 0; i < 4; ++i) {
#pragma unroll
    for (int off = 1; off < 16; off <<= 1) {
      float om = __shfl_xor(m[i], off);
      float os = __shfl_xor(s[i], off);
      float nm = fmaxf(m[i], om);
      s[i] = s[i] * __expf(m[i] - nm) + os * __expf(om - nm);
      m[i] = nm;
    }
  }
  float inv[4];
#pragma unroll
  for (int i = 0; i < 4; ++i) inv[i] = 1.f / s[i];

  // ---------------- Pass B: normalize, write attn, P*V ----------------
  const bf16_t* vbase = Vt + ((size_t)bh * 64 + r) * 2048 + quad * 8;
  f32x4 pv[4] = {};

  for (int n0 = 0; n0 < 2048; n0 += 64) {
    f32x4 acc[4] = {};
#pragma unroll
    for (int tt = 0; tt < 4; ++tt) {
      const bf16_t* kr = kbase + (size_t)(n0 + tt * 16 + r) * 1024;
      acc[tt] = MFMA16(qf0, *(const bf16x8*)kr, acc[tt]);
      acc[tt] = MFMA16(qf1, *(const bf16x8*)(kr + 32), acc[tt]);
    }
#pragma unroll
    for (int tt = 0; tt < 4; ++tt)
#pragma unroll
      for (int i = 0; i < 4; ++i) {
        int row = m0 + quad * 4 + i;
        int col = n0 + tt * 16 + r;
        float v = acc[tt][i] * 0.125f;
        if (mrow[(size_t)row * 2048 + col] == 0) v = -1e9f;
        float p = __expf(v - m[i]) * inv[i];
        __builtin_nontemporal_store(p, &arow[(size_t)row * 2048 + col]);
        T[wid][quad * 4 + i][tt * 16 + r] = p;
      }
#pragma unroll
    for (int ks = 0; ks < 2; ++ks) {
      bf16x8 af = loadfrag(&T[wid][r][ks * 32 + quad * 8]);
#pragma unroll
      for (int tt2 = 0; tt2 < 4; ++tt2) {
        const bf16_t* vr = vbase + (size_t)tt2 * 16 * 2048 + n0 + ks * 32;
        pv[tt2] = MFMA16(af, *(const bf16x8*)vr, pv[tt2]);
      }
    }
  }

#pragma unroll
  for (int tt2 = 0; tt2 < 4; ++tt2)
#pragma unroll
    for (int i = 0; i < 4; ++i) {
      int row = m0 + quad * 4 + i;
      int col = tt2 * 16 + r;
      ctx[((size_t)b * 2048 + row) * 1024 + h * 64 + col] = (bf16_t)pv[tt2][i];
    }
}

extern "C" void kernel_launch(void* const* d_in, const int* in_sizes, int n_in,
                              void* d_out, int out_size, void* d_ws, size_t ws_size,
                              hipStream_t stream) {
  const float* x    = (const float*)d_in[0];
  const int*   mask = (const int*)d_in[1];
  const float* wq_w = (const float*)d_in[2];
  const float* wq_b = (const float*)d_in[3];
  const float* wk_w = (const float*)d_in[4];
  const float* wk_b = (const float*)d_in[5];
  const float* wv_w = (const float*)d_in[6];
  const float* wv_b = (const float*)d_in[7];
  const float* wo_w = (const float*)d_in[8];
  const float* wo_b = (const float*)d_in[9];

  float* out  = (float*)d_out;
  float* attn = out + (size_t)2 * 2048 * 1024;

  // bf16 scratch in the (currently dead) attn output region:
  char* scr = (char*)attn;
  bf16_t* xb  = (bf16_t*)scr;                        // 8 MB
  bf16_t* wqb = (bf16_t*)(scr + (8u << 20));         // 2 MB
  bf16_t* wkb = (bf16_t*)(scr + (10u << 20));        // 2 MB
  bf16_t* wvb = (bf16_t*)(scr + (12u << 20));        // 2 MB

  const size_t MB8 = (size_t)4096 * 1024;  // elements per 4096x1024 bf16 buffer
  bf16_t* qbuf = (bf16_t*)d_ws;
  bf16_t* kbuf = qbuf + MB8;
  bf16_t* vtb  = qbuf + 2 * MB8;
  bf16_t* ctx  = qbuf;   // reuse q slot (per-wave exact self-overwrite)
  bf16_t* wob  = kbuf;   // reuse k slot AFTER attn_fused_k (kbuf dead by then)

  dim3 blk(256);
  cvt_k<<<2048, blk, 0, stream>>>(x, xb, 524288);
  cvt_k<<<512, blk, 0, stream>>>(wq_w, wqb, 131072);
  cvt_k<<<512, blk, 0, stream>>>(wk_w, wkb, 131072);
  cvt_k<<<512, blk, 0, stream>>>(wv_w, wvb, 131072);
  gemm128_k<0, bf16_t><<<512, blk, 0, stream>>>(xb, wqb, wq_b, qbuf);
  gemm128_k<0, bf16_t><<<512, blk, 0, stream>>>(xb, wkb, wk_b, kbuf);
  gemm128_k<1, bf16_t><<<512, blk, 0, stream>>>(xb, wvb, wv_b, vtb);
  attn_fused_k<<<1024, blk, 0, stream>>>(qbuf, kbuf, vtb, mask, attn, ctx);
  cvt_k<<<512, blk, 0, stream>>>(wo_w, wob, 131072);
  gemm128_k<0, float><<<512, blk, 0, stream>>>(ctx, wob, wo_b, out);
}